// Round 7
// baseline (32.595 us; speedup 1.0000x reference)
//
#include <hip/hip_runtime.h>
#include <math.h>

// STP forward as affine recurrence on r = imu/mu:
//   d[n] = a + (x[n-1]+x[n])/2
//   r[n] = exp(-d[n]) * (r[n-1] + x[n-1]/2) + x[n]/2
// td[n] = (r[n] > 0) ? 1 - r[n] : 1 ; chunk(500)-boundary carry clamp r>0?r:1.
// Carry into a chunk decays by exp(-(500a+trapz)) <= ~1e-11 -> each chunk's
// raw end (rraw) is computed carry-free from its own 20 segment (A,B)s.
//
// r7 = r3 structure (kA: segment (A,B) + LDS scan -> (P,Q), rraw;
//                    kB: r_in = P*clamp(rraw[c-1])+Q, f32 replay)
// + FULL float4 vectorization: each thread owns 4 consecutive u-channels,
//   so every global load/store is 16 B/lane and phase-1 runs 4 independent
//   Taylor chains per thread (ILP on the 12-FMA Horner dependency).

#define TDIM 50000
#define UDIM 16
#define NCH 100
#define SEG 20      // 25-step sub-segments per chunk
#define SLEN 25
#define NSEQ 128    // B*U

struct alignas(16) PQt { double P; double Q; };

__device__ __forceinline__ float cleanf(float v) { return (v != v) ? 0.0f : v; }
__device__ __forceinline__ float4 clean4(float4 v) {
    v.x = cleanf(v.x); v.y = cleanf(v.y); v.z = cleanf(v.z); v.w = cleanf(v.w);
    return v;
}
__device__ __forceinline__ float getc(const float4& v, int j) {
    return j == 0 ? v.x : (j == 1 ? v.y : (j == 2 ? v.z : v.w));
}

// exp(y) for |y| <= ~0.7, deg-11 Taylor Horner. abs err < ~2e-12 at 0.55.
__device__ __forceinline__ double exp_small(double y) {
    double p = 2.505210838544172e-8;         // 1/11!
    p = fma(p, y, 2.7557319223985893e-7);    // 1/10!
    p = fma(p, y, 2.755731922398589e-6);     // 1/9!
    p = fma(p, y, 2.48015873015873e-5);      // 1/8!
    p = fma(p, y, 1.984126984126984e-4);     // 1/7!
    p = fma(p, y, 1.3888888888888889e-3);    // 1/6!
    p = fma(p, y, 8.333333333333333e-3);     // 1/5!
    p = fma(p, y, 4.1666666666666664e-2);    // 1/4!
    p = fma(p, y, 1.6666666666666666e-1);    // 1/3!
    p = fma(p, y, 0.5);                      // 1/2!
    p = fma(p, y, 1.0);
    p = fma(p, y, 1.0);
    return p;
}

// kA: grid 200 blocks x 320 thr. Block = (chunk c, 4 batches).
// Thread = (bl 0..3, s 0..19, q 0..3): segment s of chunk c, batch b,
// u-channels 4q..4q+3. float4 loads; (A,B) per channel; LDS scan -> (P,Q).
__global__ __launch_bounds__(320) void stp_kA(
    const float* __restrict__ inp, const float* __restrict__ uu,
    const float* __restrict__ tauv, PQt* __restrict__ PQ,
    double* __restrict__ rraw)
{
    const int c    = blockIdx.x >> 1;
    const int half = blockIdx.x & 1;
    const int tid  = threadIdx.x;
    const int bl   = tid / 80;
    const int rem  = tid - bl * 80;
    const int s    = rem >> 2;
    const int q    = rem & 3;
    const int b    = half * 4 + bl;
    const int u0   = q * 4;
    const int n0   = c * 500 + s * SLEN;

    // Replicate reference f32 -> f64 promotion exactly (per channel):
    float uif[4]; double ea[4];
    #pragma unroll
    for (int j = 0; j < 4; ++j) {
        const int u = u0 + j;
        uif[j] = (fabsf(uu[u]) / 100.0f) * 100.0f;
        const float taui = fmaxf(fabsf(tauv[u]), 0.02001f) * 100.0f;
        ea[j] = exp_small(-(double)(1.0f / taui));   // a <= 0.4998: in range
    }

    const float4* p4 = (const float4*)(inp + ((size_t)b * TDIM + n0) * UDIM + u0);

    double xp[4], ep[4], A[4], B[4];
    {
        float4 xv = make_float4(0.f, 0.f, 0.f, 0.f);
        if (n0 != 0) xv = clean4(p4[-4]);
        #pragma unroll
        for (int j = 0; j < 4; ++j) {
            xp[j] = (double)(uif[j] * getc(xv, j));
            ep[j] = exp_small(-0.5 * xp[j]);
            A[j] = 1.0; B[j] = 0.0;
        }
    }
#pragma unroll 5
    for (int t = 0; t < SLEN; ++t) {
        const float4 v = clean4(p4[t * 4]);
        #pragma unroll
        for (int j = 0; j < 4; ++j) {
            const double x  = (double)(uif[j] * getc(v, j));
            const double ex = exp_small(-0.5 * x);
            const double e  = ea[j] * ep[j] * ex;    // exp(-(a+(xp+x)/2))
            A[j] *= e;
            B[j] = fma(e, fma(xp[j], 0.5, B[j]), 0.5 * x);
            ep[j] = ex; xp[j] = x;
        }
    }

    __shared__ double sA[4][SEG][16];
    __shared__ double sB[4][SEG][16];
    #pragma unroll
    for (int j = 0; j < 4; ++j) { sA[bl][s][u0 + j] = A[j]; sB[bl][s][u0 + j] = B[j]; }
    __syncthreads();

    // exclusive prefix over segs 0..s-1: r_in(seg s) = P*r_chunk_in + Q
    double P[4] = {1.0, 1.0, 1.0, 1.0}, Q[4] = {0.0, 0.0, 0.0, 0.0};
    for (int k = 0; k < s; ++k) {
        #pragma unroll
        for (int j = 0; j < 4; ++j) {
            const double Ak = sA[bl][k][u0 + j];
            const double Bk = sB[bl][k][u0 + j];
            P[j] *= Ak;
            Q[j] = fma(Ak, Q[j], Bk);
        }
    }

    const int sbu = b * 16 + u0;
    PQt* dst = PQ + (size_t)(c * SEG + s) * NSEQ + sbu;
    #pragma unroll
    for (int j = 0; j < 4; ++j) { dst[j].P = P[j]; dst[j].Q = Q[j]; }
    if (s == SEG - 1) {
        #pragma unroll
        for (int j = 0; j < 4; ++j)
            rraw[(size_t)c * NSEQ + sbu + j] = fma(A[j], Q[j], B[j]);
    }
}

// kB: grid 250 x 256 = 64000 thr. Thread = (seg, b, q): 25-step f32 replay
// of 4 u-channels, float4 in / float4 out.
__global__ __launch_bounds__(256) void stp_kB(
    const float* __restrict__ inp, const float* __restrict__ uu,
    const float* __restrict__ tauv, const PQt* __restrict__ PQ,
    const double* __restrict__ rraw, float* __restrict__ out)
{
    const int g   = blockIdx.x * 256 + threadIdx.x;
    const int q   = g & 3;
    const int b   = (g >> 2) & 7;
    const int seg = g >> 5;                   // 0..1999
    const int c   = seg / SEG;
    const int s   = seg - c * SEG;
    const int u0  = q * 4;
    const int sbu = b * 16 + u0;
    const int n0  = seg * SLEN;

    float uif[4], aff[4];
    #pragma unroll
    for (int j = 0; j < 4; ++j) {
        const int u = u0 + j;
        uif[j] = (fabsf(uu[u]) / 100.0f) * 100.0f;
        const float taui = fmaxf(fabsf(tauv[u]), 0.02001f) * 100.0f;
        aff[j] = 1.0f / taui;
    }

    const PQt* pq = PQ + (size_t)seg * NSEQ + sbu;
    float r[4], tdp[4];
    #pragma unroll
    for (int j = 0; j < 4; ++j) {
        double carry, tdp_d;
        if (c > 0) {
            const double re = rraw[(size_t)(c - 1) * NSEQ + sbu + j];
            carry = (re > 0.0) ? re : 1.0;        // clamped carry
            tdp_d = (re > 0.0) ? 1.0 - re : 1.0;  // td from RAW prev-chunk end
        } else {
            carry = 0.0;                           // chunk 0: imu0 = 0
            tdp_d = 1.0;                           // out[0] pad value
        }
        const double r_in = fma(pq[j].P, carry, pq[j].Q);
        if (s > 0) tdp_d = (r_in > 0.0) ? 1.0 - r_in : 1.0;
        r[j] = (float)r_in;
        tdp[j] = (float)tdp_d;
    }

    const float4* p4 = (const float4*)(inp + ((size_t)b * TDIM + n0) * UDIM + u0);
    float4*       o4 = (float4*)(out + ((size_t)b * TDIM + n0) * UDIM + u0);

    float xpf[4];
    {
        float4 xv = make_float4(0.f, 0.f, 0.f, 0.f);
        if (n0 != 0) xv = clean4(p4[-4]);
        #pragma unroll
        for (int j = 0; j < 4; ++j) xpf[j] = uif[j] * getc(xv, j);
    }
#pragma unroll 5
    for (int t = 0; t < SLEN; ++t) {
        const float4 v = clean4(p4[t * 4]);
        float4 st;
        #pragma unroll
        for (int j = 0; j < 4; ++j) {
            const float ts = getc(v, j);
            const float x  = uif[j] * ts;
            const float d  = aff[j] + (xpf[j] + x) * 0.5f;
            const float e  = __expf(-d);
            r[j] = e * (r[j] + xpf[j] * 0.5f) + x * 0.5f;
            const float ov = ts * tdp[j];          // out[n] = tstim[n]*td[n-1]
            tdp[j] = (r[j] > 0.0f) ? 1.0f - r[j] : 1.0f;
            xpf[j] = x;
            if (j == 0) st.x = ov; else if (j == 1) st.y = ov;
            else if (j == 2) st.z = ov; else st.w = ov;
        }
        o4[t * 4] = st;
    }
}

extern "C" void kernel_launch(void* const* d_in, const int* in_sizes, int n_in,
                              void* d_out, int out_size, void* d_ws, size_t ws_size,
                              hipStream_t stream) {
    const float* inp  = (const float*)d_in[0];
    const float* uu   = (const float*)d_in[1];
    const float* tauv = (const float*)d_in[2];
    float* out = (float*)d_out;

    PQt*    PQ   = (PQt*)d_ws;                          // 4,096,000 B
    double* rraw = (double*)((char*)d_ws + 4096000);    // 102,400 B

    stp_kA<<<dim3(200), dim3(320), 0, stream>>>(inp, uu, tauv, PQ, rraw);
    stp_kB<<<dim3(250), dim3(256), 0, stream>>>(inp, uu, tauv, PQ, rraw, out);
}

// Round 9
// 26.932 us; speedup vs baseline: 1.2103x; 1.2103x over previous
//
#include <hip/hip_runtime.h>
#include <math.h>

// STP forward as affine recurrence on r = imu/mu:
//   d[n] = a + (x[n-1]+x[n])/2
//   r[n] = exp(-d[n]) * (r[n-1] + x[n-1]/2) + x[n]/2
// td[n] = (r[n] > 0) ? 1 - r[n] : 1 ; chunk(500)-boundary carry clamp r>0?r:1.
// Carry into a chunk decays by exp(-(500a+trapz)) <= ~1e-11 -> the raw chunk
// end rp (clamp driver) is a pure function of that chunk's 500 inputs, so
// each block recomputes chunk c-1 locally: no cross-block dep, one kernel.
//
// ALL-F32 version (r8 retry; r8's failure was an af transcription bug:
// 1/x/0.01 = 100/x instead of the reference's 1/(x*100) = 0.01/x).
// f32 rp error ~5e-7 vs rp sigma ~0.1 -> clamp-flip prob ~3% total; fail
// mode would be absmax O(1) -> revert L-chain to f64.
// Phase 1 caches ts[25] and e[25] in registers -> phase-2 replay has zero
// loads / zero transcendentals. Block = (chunk c, batch b), 320 thr =
// 20 seg x 16 u; f32 LDS scan composes segment (A,B).

#define TDIM 50000
#define UDIM 16
#define NCH 100
#define SEG 20      // 25-step sub-segments per chunk
#define SLEN 25
#define NSEQ 128    // B*U

__device__ __forceinline__ float clean(float v) { return (v != v) ? 0.0f : v; }

__global__ __launch_bounds__(320) void stp_one(
    const float* __restrict__ inp, const float* __restrict__ uu,
    const float* __restrict__ tauv, float* __restrict__ out)
{
    const int c = blockIdx.x >> 3;           // chunk 0..99
    const int b = blockIdx.x & 7;            // batch 0..7 (== XCD id)
    const int s = threadIdx.x >> 4;          // seg-in-chunk 0..19
    const int u = threadIdx.x & 15;
    const int cm1 = (c > 0) ? c - 1 : 0;     // c==0: L-chain junk, discarded
    const int n0R = c   * 500 + s * SLEN;
    const int n0L = cm1 * 500 + s * SLEN;

    // Reference's parameter prep, exact f32 form used in rounds 1-7:
    const float ui   = (fabsf(uu[u]) / 100.0f) * 100.0f;
    const float taui = fmaxf(fabsf(tauv[u]), 0.02001f) * 100.0f;
    const float af   = 1.0f / taui;

    const float* pL = inp + ((size_t)b * TDIM + n0L) * UDIM + u;
    const float* pR = inp + ((size_t)b * TDIM + n0R) * UDIM + u;

    // ---- phase 1: two interleaved f32 affine chains; cache ts,e for R ----
    float tsR[SLEN], eR[SLEN];               // fully unrolled -> registers
    float xpL = (n0L != 0) ? ui * clean(pL[-UDIM]) : 0.0f;
    float xpR = (n0R != 0) ? ui * clean(pR[-UDIM]) : 0.0f;
    float AL = 1.0f, BL = 0.0f, AR = 1.0f, BR = 0.0f;
#pragma unroll
    for (int t = 0; t < SLEN; ++t) {
        const float tL = clean(pL[(size_t)t * UDIM]);
        const float tR = clean(pR[(size_t)t * UDIM]);
        tsR[t] = tR;
        const float xL = ui * tL;
        const float xR = ui * tR;
        const float eL = __expf(-(af + (xpL + xL) * 0.5f));
        const float eX = __expf(-(af + (xpR + xR) * 0.5f));
        eR[t] = eX;
        AL *= eL;  BL = eL * (BL + xpL * 0.5f) + xL * 0.5f;
        AR *= eX;  BR = eX * (BR + xpR * 0.5f) + xR * 0.5f;
        xpL = xL;  xpR = xR;
    }

    __shared__ float sAL[SEG][16], sBL[SEG][16];
    __shared__ float sAR[SEG][16], sBR[SEG][16];
    sAL[s][u] = AL; sBL[s][u] = BL;
    sAR[s][u] = AR; sBR[s][u] = BR;
    __syncthreads();

    // raw end of chunk c-1 from entry 0 (A-products underflow->0 harmlessly,
    // matching the true e^-250-scale decay)
    float rp = 0.0f;
#pragma unroll
    for (int j = 0; j < SEG; ++j) rp = fmaf(sAL[j][u], rp, sBL[j][u]);

    // exclusive prefix over own chunk's segs 0..s-1: r_in = P*carry + Q
    float P = 1.0f, Q = 0.0f;
    for (int j = 0; j < s; ++j) {
        const float Aj = sAR[j][u];
        const float Bj = sBR[j][u];
        P *= Aj;
        Q = fmaf(Aj, Q, Bj);
    }

    float carry, tdp;
    if (c > 0) {
        carry = (rp > 0.0f) ? rp : 1.0f;        // clamped carry
        tdp   = (rp > 0.0f) ? 1.0f - rp : 1.0f; // td from RAW prev-chunk end
    } else {
        carry = 0.0f;                            // chunk 0: imu0 = 0
        tdp   = 1.0f;                            // out[0] uses pad value 1.0
    }
    float r = fmaf(P, carry, Q);
    if (s > 0) tdp = (r > 0.0f) ? 1.0f - r : 1.0f;

    // ---- phase 2: replay from register caches (no loads, no exp) ----
    float* o = out + ((size_t)b * TDIM + n0R) * UDIM + u;
    float xp = (n0R != 0) ? ui * clean(pR[-UDIM]) : 0.0f;
#pragma unroll
    for (int t = 0; t < SLEN; ++t) {
        const float ts = tsR[t];
        const float x  = ui * ts;
        r = eR[t] * (r + xp * 0.5f) + x * 0.5f;
        o[(size_t)t * UDIM] = ts * tdp;          // out[n] = tstim[n]*td[n-1]
        tdp = (r > 0.0f) ? 1.0f - r : 1.0f;
        xp = x;
    }
}

extern "C" void kernel_launch(void* const* d_in, const int* in_sizes, int n_in,
                              void* d_out, int out_size, void* d_ws, size_t ws_size,
                              hipStream_t stream) {
    const float* inp  = (const float*)d_in[0];
    const float* uu   = (const float*)d_in[1];
    const float* tauv = (const float*)d_in[2];
    float* out = (float*)d_out;

    stp_one<<<dim3(NCH * 8), dim3(320), 0, stream>>>(inp, uu, tauv, out);
}

// Round 10
// 21.453 us; speedup vs baseline: 1.5194x; 1.2554x over previous
//
#include <hip/hip_runtime.h>
#include <math.h>

// STP forward as affine recurrence on r = imu/mu:
//   d[n] = a + (x[n-1]+x[n])/2
//   r[n] = exp(-d[n]) * (r[n-1] + x[n-1]/2) + x[n]/2
// td[n] = (r[n] > 0) ? 1 - r[n] : 1 ; chunk(500)-boundary carry clamp r>0?r:1.
// Carry into a chunk decays by exp(-(500a+trapz)) <= ~1e-11 -> each chunk's
// raw end (rraw, the clamp driver) is computed carry-free from its own 20
// segment (A,B)s.
//
// r10 = minimal all-f32 two-kernel pipeline (1x phase-1 work):
//   kA: f32 segment (A,B) via hw __expf, LDS scan -> per-seg (P,Q) f32 +
//       rraw per chunk.  kB: r_in = P*clamp(rraw[c-1]) + Q (1 fma), then
//       25-step f32 replay. Per-element math identical to r9 (passed,
//       absmax 0.0039).

#define TDIM 50000
#define UDIM 16
#define NCH 100
#define SEG 20      // 25-step sub-segments per chunk
#define SLEN 25
#define NSEQ 128    // B*U

__device__ __forceinline__ float clean(float v) { return (v != v) ? 0.0f : v; }

// kA: block = (chunk c, batch b), 320 thr = 20 seg x 16 u.
__global__ __launch_bounds__(320) void stp_kA(
    const float* __restrict__ inp, const float* __restrict__ uu,
    const float* __restrict__ tauv, float2* __restrict__ PQ,
    float* __restrict__ rraw)
{
    const int c = blockIdx.x >> 3;           // chunk 0..99
    const int b = blockIdx.x & 7;            // batch 0..7
    const int s = threadIdx.x >> 4;          // seg-in-chunk 0..19
    const int u = threadIdx.x & 15;
    const int n0 = c * 500 + s * SLEN;

    // Reference's parameter prep (exact f32 form from rounds 1-7,9):
    const float ui   = (fabsf(uu[u]) / 100.0f) * 100.0f;
    const float taui = fmaxf(fabsf(tauv[u]), 0.02001f) * 100.0f;
    const float af   = 1.0f / taui;

    const float* p = inp + ((size_t)b * TDIM + n0) * UDIM + u;
    float xp = (n0 != 0) ? ui * clean(p[-UDIM]) : 0.0f;
    float A = 1.0f, B = 0.0f;
#pragma unroll
    for (int t = 0; t < SLEN; ++t) {
        const float ts = clean(p[(size_t)t * UDIM]);
        const float x  = ui * ts;
        const float e  = __expf(-(af + (xp + x) * 0.5f));
        A *= e;
        B = e * (B + xp * 0.5f) + x * 0.5f;
        xp = x;
    }

    __shared__ float sA[SEG][16], sB[SEG][16];
    sA[s][u] = A; sB[s][u] = B;
    __syncthreads();

    // exclusive prefix over segs 0..s-1: r_in(seg s) = P*r_chunk_in + Q
    float P = 1.0f, Q = 0.0f;
    for (int j = 0; j < s; ++j) {
        const float Aj = sA[j][u];
        const float Bj = sB[j][u];
        P *= Aj;
        Q = fmaf(Aj, Q, Bj);
    }

    const int sbu = b * 16 + u;
    PQ[(size_t)(c * SEG + s) * NSEQ + sbu] = make_float2(P, Q);
    if (s == SEG - 1) {
        // raw chunk end from entry 0 (A-products underflow->0 harmlessly)
        rraw[(size_t)c * NSEQ + sbu] = fmaf(A, Q, B);
    }
}

// kB: one thread per (seg, sbu); 1000 blocks x 256.
__global__ __launch_bounds__(256) void stp_kB(
    const float* __restrict__ inp, const float* __restrict__ uu,
    const float* __restrict__ tauv, const float2* __restrict__ PQ,
    const float* __restrict__ rraw, float* __restrict__ out)
{
    const int g   = blockIdx.x * 256 + threadIdx.x;
    const int sbu = g & (NSEQ - 1);
    const int seg = g >> 7;                  // 0..1999
    const int c   = seg / SEG;
    const int s   = seg - c * SEG;
    const int u   = sbu & 15;
    const int b   = sbu >> 4;
    const int n0  = seg * SLEN;

    const float ui   = (fabsf(uu[u]) / 100.0f) * 100.0f;
    const float taui = fmaxf(fabsf(tauv[u]), 0.02001f) * 100.0f;
    const float af   = 1.0f / taui;

    const float2 pq = PQ[(size_t)seg * NSEQ + sbu];
    float carry, tdp;
    if (c > 0) {
        const float re = rraw[(size_t)(c - 1) * NSEQ + sbu];
        carry = (re > 0.0f) ? re : 1.0f;        // clamped carry
        tdp   = (re > 0.0f) ? 1.0f - re : 1.0f; // td from RAW prev-chunk end
    } else {
        carry = 0.0f;                            // chunk 0: imu0 = 0
        tdp   = 1.0f;                            // out[0] uses pad value 1.0
    }
    float r = fmaf(pq.x, carry, pq.y);
    if (s > 0) tdp = (r > 0.0f) ? 1.0f - r : 1.0f;

    const float* p = inp + ((size_t)b * TDIM + n0) * UDIM + u;
    float*       o = out + ((size_t)b * TDIM + n0) * UDIM + u;
    float xp = (n0 != 0) ? ui * clean(p[-UDIM]) : 0.0f;
#pragma unroll
    for (int t = 0; t < SLEN; ++t) {
        const float ts = clean(p[(size_t)t * UDIM]);
        const float x  = ui * ts;
        const float e  = __expf(-(af + (xp + x) * 0.5f));
        r = e * (r + xp * 0.5f) + x * 0.5f;
        o[(size_t)t * UDIM] = ts * tdp;          // out[n] = tstim[n]*td[n-1]
        tdp = (r > 0.0f) ? 1.0f - r : 1.0f;
        xp = x;
    }
}

extern "C" void kernel_launch(void* const* d_in, const int* in_sizes, int n_in,
                              void* d_out, int out_size, void* d_ws, size_t ws_size,
                              hipStream_t stream) {
    const float* inp  = (const float*)d_in[0];
    const float* uu   = (const float*)d_in[1];
    const float* tauv = (const float*)d_in[2];
    float* out = (float*)d_out;

    float2* PQ   = (float2*)d_ws;                       // 2,048,000 B
    float*  rraw = (float*)((char*)d_ws + 2048000);     // 51,200 B

    stp_kA<<<dim3(NCH * 8), dim3(320), 0, stream>>>(inp, uu, tauv, PQ, rraw);
    stp_kB<<<dim3(1000), dim3(256), 0, stream>>>(inp, uu, tauv, PQ, rraw, out);
}

// Round 11
// 21.435 us; speedup vs baseline: 1.5206x; 1.0008x over previous
//
#include <hip/hip_runtime.h>
#include <math.h>

// STP forward as affine recurrence on r = imu/mu:
//   d[n] = a + (x[n-1]+x[n])/2
//   r[n] = exp(-d[n]) * (r[n-1] + x[n-1]/2) + x[n]/2
// td[n] = (r[n] > 0) ? 1 - r[n] : 1 ; chunk(500)-boundary carry clamp r>0?r:1.
// Carry into a chunk decays by exp(-(500a+trapz)) <= ~1e-11 -> each chunk's
// raw end (rraw, the clamp driver) is computed carry-free from its own 20
// segment (A,B)s.
//
// r11 = r10 (best: 21.45us, absmax 0.0039) with kB micro-optimized:
//   each kB thread owns TWO adjacent u-channels -> float2 loads/stores
//   (8B/lane), PQ pair as one float4, rraw pair as one float2, and two
//   independent recurrence chains (ILP). kA unchanged from r10.
// Cost model (validated by r3->r10 delta matching f64-Horner arithmetic):
//   kA ~2.5us, kB ~4.5us (25.6MB HBM write floor ~4us), fixed ~14us.

#define TDIM 50000
#define UDIM 16
#define NCH 100
#define SEG 20      // 25-step sub-segments per chunk
#define SLEN 25
#define NSEQ 128    // B*U

__device__ __forceinline__ float clean(float v) { return (v != v) ? 0.0f : v; }

// kA: block = (chunk c, batch b), 320 thr = 20 seg x 16 u. (unchanged r10)
__global__ __launch_bounds__(320) void stp_kA(
    const float* __restrict__ inp, const float* __restrict__ uu,
    const float* __restrict__ tauv, float2* __restrict__ PQ,
    float* __restrict__ rraw)
{
    const int c = blockIdx.x >> 3;           // chunk 0..99
    const int b = blockIdx.x & 7;            // batch 0..7
    const int s = threadIdx.x >> 4;          // seg-in-chunk 0..19
    const int u = threadIdx.x & 15;
    const int n0 = c * 500 + s * SLEN;

    // Reference's parameter prep (exact f32 form):
    const float ui   = (fabsf(uu[u]) / 100.0f) * 100.0f;
    const float taui = fmaxf(fabsf(tauv[u]), 0.02001f) * 100.0f;
    const float af   = 1.0f / taui;

    const float* p = inp + ((size_t)b * TDIM + n0) * UDIM + u;
    float xp = (n0 != 0) ? ui * clean(p[-UDIM]) : 0.0f;
    float A = 1.0f, B = 0.0f;
#pragma unroll
    for (int t = 0; t < SLEN; ++t) {
        const float ts = clean(p[(size_t)t * UDIM]);
        const float x  = ui * ts;
        const float e  = __expf(-(af + (xp + x) * 0.5f));
        A *= e;
        B = e * (B + xp * 0.5f) + x * 0.5f;
        xp = x;
    }

    __shared__ float sA[SEG][16], sB[SEG][16];
    sA[s][u] = A; sB[s][u] = B;
    __syncthreads();

    // exclusive prefix over segs 0..s-1: r_in(seg s) = P*r_chunk_in + Q
    float P = 1.0f, Q = 0.0f;
    for (int j = 0; j < s; ++j) {
        const float Aj = sA[j][u];
        const float Bj = sB[j][u];
        P *= Aj;
        Q = fmaf(Aj, Q, Bj);
    }

    const int sbu = b * 16 + u;
    PQ[(size_t)(c * SEG + s) * NSEQ + sbu] = make_float2(P, Q);
    if (s == SEG - 1) {
        // raw chunk end from entry 0 (A-products underflow->0 harmlessly)
        rraw[(size_t)c * NSEQ + sbu] = fmaf(A, Q, B);
    }
}

// kB: one thread per (seg, b, u-pair); 500 blocks x 256 = 128k threads.
// Wave = one seg covering all 64 (b, u-pair) -> full 64B-line coalescing,
// 8B/lane float2 traffic, two independent chains per thread.
__global__ __launch_bounds__(256) void stp_kB(
    const float* __restrict__ inp, const float* __restrict__ uu,
    const float* __restrict__ tauv, const float2* __restrict__ PQ,
    const float* __restrict__ rraw, float* __restrict__ out)
{
    const int g   = blockIdx.x * 256 + threadIdx.x;
    const int u2  = g & 7;                   // u-pair 0..7 (u0 = 2*u2)
    const int b   = (g >> 3) & 7;
    const int seg = g >> 6;                  // 0..1999
    const int c   = seg / SEG;
    const int s   = seg - c * SEG;
    const int u0  = u2 * 2;
    const int sbu = b * 16 + u0;
    const int n0  = seg * SLEN;

    const float ui0 = (fabsf(uu[u0])     / 100.0f) * 100.0f;
    const float ui1 = (fabsf(uu[u0 + 1]) / 100.0f) * 100.0f;
    const float af0 = 1.0f / (fmaxf(fabsf(tauv[u0]),     0.02001f) * 100.0f);
    const float af1 = 1.0f / (fmaxf(fabsf(tauv[u0 + 1]), 0.02001f) * 100.0f);

    // PQ for the two channels: 16B-aligned contiguous pair -> one float4.
    const float4 pq = *(const float4*)(PQ + (size_t)seg * NSEQ + sbu);
    float r0, r1, tdp0, tdp1;
    {
        float c0, c1, t0, t1;
        if (c > 0) {
            const float2 re = *(const float2*)(rraw + (size_t)(c - 1) * NSEQ + sbu);
            c0 = (re.x > 0.0f) ? re.x : 1.0f;       // clamped carry
            c1 = (re.y > 0.0f) ? re.y : 1.0f;
            t0 = (re.x > 0.0f) ? 1.0f - re.x : 1.0f; // td from RAW prev end
            t1 = (re.y > 0.0f) ? 1.0f - re.y : 1.0f;
        } else {
            c0 = c1 = 0.0f;                          // chunk 0: imu0 = 0
            t0 = t1 = 1.0f;                          // out[0] pad value
        }
        r0 = fmaf(pq.x, c0, pq.y);
        r1 = fmaf(pq.z, c1, pq.w);
        if (s > 0) {
            t0 = (r0 > 0.0f) ? 1.0f - r0 : 1.0f;
            t1 = (r1 > 0.0f) ? 1.0f - r1 : 1.0f;
        }
        tdp0 = t0; tdp1 = t1;
    }

    const float2* p2 = (const float2*)(inp + ((size_t)b * TDIM + n0) * UDIM + u0);
    float2*       o2 = (float2*)(out + ((size_t)b * TDIM + n0) * UDIM + u0);

    float xp0 = 0.0f, xp1 = 0.0f;
    if (n0 != 0) {
        const float2 xv = p2[-8];
        xp0 = ui0 * clean(xv.x);
        xp1 = ui1 * clean(xv.y);
    }
#pragma unroll
    for (int t = 0; t < SLEN; ++t) {
        const float2 v = p2[t * 8];
        const float ts0 = clean(v.x);
        const float ts1 = clean(v.y);
        const float x0  = ui0 * ts0;
        const float x1  = ui1 * ts1;
        const float e0  = __expf(-(af0 + (xp0 + x0) * 0.5f));
        const float e1  = __expf(-(af1 + (xp1 + x1) * 0.5f));
        r0 = e0 * (r0 + xp0 * 0.5f) + x0 * 0.5f;
        r1 = e1 * (r1 + xp1 * 0.5f) + x1 * 0.5f;
        o2[t * 8] = make_float2(ts0 * tdp0, ts1 * tdp1);  // out[n]=ts*td[n-1]
        tdp0 = (r0 > 0.0f) ? 1.0f - r0 : 1.0f;
        tdp1 = (r1 > 0.0f) ? 1.0f - r1 : 1.0f;
        xp0 = x0; xp1 = x1;
    }
}

extern "C" void kernel_launch(void* const* d_in, const int* in_sizes, int n_in,
                              void* d_out, int out_size, void* d_ws, size_t ws_size,
                              hipStream_t stream) {
    const float* inp  = (const float*)d_in[0];
    const float* uu   = (const float*)d_in[1];
    const float* tauv = (const float*)d_in[2];
    float* out = (float*)d_out;

    float2* PQ   = (float2*)d_ws;                       // 2,048,000 B
    float*  rraw = (float*)((char*)d_ws + 2048000);     // 51,200 B

    stp_kA<<<dim3(NCH * 8), dim3(320), 0, stream>>>(inp, uu, tauv, PQ, rraw);
    stp_kB<<<dim3(500), dim3(256), 0, stream>>>(inp, uu, tauv, PQ, rraw, out);
}